// Round 8
// baseline (529.925 us; speedup 1.0000x reference)
//
#include <hip/hip_runtime.h>
#include <hip/hip_cooperative_groups.h>
#include <math.h>

// CausalRevIN: B=16, T=8192, C=128, fp32.
// R8: single cooperative kernel. Block = (b, 128-row chunk), 1024 blocks.
// x read ONCE into registers; mask ONCE -> nm nibbles in LDS; two grid.sync()s
// with per-block O(k) predecessor-aggregate sums replace the scan kernels.
// Fallback (coop launch failure): R6's 5-kernel path.
constexpr int B = 16;
constexpr int T = 8192;
constexpr int C = 128;
constexpr int CG = C / 4;        // 32 f32x4 channel-groups
constexpr int TBK = 128;         // rows per block (fused kernel)
constexpr int NCH = T / TBK;     // 64 chunks per batch
constexpr int SUBS = 8;
constexpr int RPT = TBK / SUBS;  // 16 rows per thread
constexpr float STD_MIN = 1e-5f;
constexpr float MAX_VAL = 100.0f;

using f32x4 = __attribute__((ext_vector_type(4))) float;

__device__ inline f32x4 sel_neff(f32x4 n) {
    f32x4 r;
    #pragma unroll
    for (int j = 0; j < 4; ++j) r[j] = (n[j] == 0.0f) ? 1.0f : n[j];
    return r;
}
__device__ inline f32x4 rcp4(f32x4 a) {
    f32x4 r;
    #pragma unroll
    for (int j = 0; j < 4; ++j) r[j] = __builtin_amdgcn_rcpf(a[j]);
    return r;
}
__device__ inline f32x4 sqrt4(f32x4 a) {
    f32x4 r;
    #pragma unroll
    for (int j = 0; j < 4; ++j) r[j] = __builtin_amdgcn_sqrtf(a[j]);
    return r;
}
__device__ inline f32x4 decode_nib(unsigned nib) {
    f32x4 r;
    r[0] = (float)(nib & 1u);
    r[1] = (float)((nib >> 1) & 1u);
    r[2] = (float)((nib >> 2) & 1u);
    r[3] = (float)((nib >> 3) & 1u);
    return r;
}

// ======================= fused cooperative kernel ==========================
__global__ __launch_bounds__(256, 4) void k_fused(
    const f32x4* __restrict__ x, const f32x4* __restrict__ mask,
    f32x4* __restrict__ out,
    f32x4* __restrict__ aggx, f32x4* __restrict__ aggn,
    f32x4* __restrict__ aggd)
{
    namespace cg = cooperative_groups;
    cg::grid_group gridg = cg::this_grid();

    __shared__ unsigned char nmb[TBK * CG];       // 4 KB nm nibbles
    __shared__ f32x4 p0[SUBS][CG], p1[SUBS][CG];  // 8 KB reduce scratch

    int tid = threadIdx.x, cgi = tid & 31, sub = tid >> 5;
    int blk = blockIdx.x, b = blk >> 6, k = blk & (NCH - 1);
    size_t gbase = ((size_t)b * T + (size_t)k * TBK) * CG + cgi;

    // ---- phase A: load x (kept in regs) + mask once; column sums ----------
    f32x4 xr[RPT];
    f32x4 sx = {0,0,0,0}, sn = {0,0,0,0};
    #pragma unroll
    for (int r = 0; r < RPT; ++r) {
        int row = sub * RPT + r;
        f32x4 xv = x[gbase + (size_t)row * CG];
        f32x4 mv = mask[gbase + (size_t)row * CG];
        xr[r] = xv;
        f32x4 nm = 1.0f - mv;
        sx += xv; sn += nm;
        unsigned nib = (unsigned)nm[0] | ((unsigned)nm[1] << 1)
                     | ((unsigned)nm[2] << 2) | ((unsigned)nm[3] << 3);
        nmb[row * CG + cgi] = (unsigned char)nib;
    }
    p0[sub][cgi] = sx; p1[sub][cgi] = sn;
    __syncthreads();
    f32x4 offx = {0,0,0,0}, offn = {0,0,0,0};
    f32x4 totx = {0,0,0,0}, totn = {0,0,0,0};
    #pragma unroll
    for (int s = 0; s < SUBS; ++s) {
        f32x4 a = p0[s][cgi], c = p1[s][cgi];
        if (s < sub) { offx += a; offn += c; }
        totx += a; totn += c;
    }
    if (sub == 0) {
        aggx[((size_t)b * NCH + k) * CG + cgi] = totx;
        aggn[((size_t)b * NCH + k) * CG + cgi] = totn;
    }
    __threadfence();
    gridg.sync();

    // ---- prefix1: sum predecessor aggregates (parallel over subs) ---------
    f32x4 pxp = {0,0,0,0}, pnp = {0,0,0,0};
    for (int j = sub; j < k; j += SUBS) {
        pxp += aggx[((size_t)b * NCH + j) * CG + cgi];
        pnp += aggn[((size_t)b * NCH + j) * CG + cgi];
    }
    p0[sub][cgi] = pxp; p1[sub][cgi] = pnp;
    __syncthreads();
    f32x4 px = {0,0,0,0}, pn = {0,0,0,0};
    #pragma unroll
    for (int s = 0; s < SUBS; ++s) { px += p0[s][cgi]; pn += p1[s][cgi]; }
    f32x4 rx0 = px + offx, rn0 = pn + offn;

    // ---- phase B: dev^2 column sums from registers ------------------------
    f32x4 rx = rx0, rn = rn0, sd = {0,0,0,0};
    #pragma unroll
    for (int r = 0; r < RPT; ++r) {
        int row = sub * RPT + r;
        f32x4 nm = decode_nib(nmb[row * CG + cgi]);
        rx += xr[r]; rn += nm;
        f32x4 mean = rx * rcp4(sel_neff(rn));
        f32x4 d = (xr[r] - mean) * nm;
        sd += d * d;
    }
    __syncthreads();
    p0[sub][cgi] = sd;
    __syncthreads();
    f32x4 offd = {0,0,0,0}, totd = {0,0,0,0};
    #pragma unroll
    for (int s = 0; s < SUBS; ++s) {
        f32x4 a = p0[s][cgi];
        if (s < sub) offd += a;
        totd += a;
    }
    if (sub == 0) aggd[((size_t)b * NCH + k) * CG + cgi] = totd;
    __threadfence();
    gridg.sync();

    // ---- prefix2 ----------------------------------------------------------
    f32x4 pdp = {0,0,0,0};
    for (int j = sub; j < k; j += SUBS)
        pdp += aggd[((size_t)b * NCH + j) * CG + cgi];
    p0[sub][cgi] = pdp;
    __syncthreads();
    f32x4 pd = {0,0,0,0};
    #pragma unroll
    for (int s = 0; s < SUBS; ++s) pd += p0[s][cgi];
    f32x4 rd = pd + offd;

    // ---- phase C: finalize + NT store ------------------------------------
    rx = rx0; rn = rn0;
    #pragma unroll
    for (int r = 0; r < RPT; ++r) {
        int row = sub * RPT + r;
        f32x4 nm = decode_nib(nmb[row * CG + cgi]);
        rx += xr[r]; rn += nm;
        f32x4 inv = rcp4(sel_neff(rn));
        f32x4 mean = rx * inv;
        f32x4 d = (xr[r] - mean) * nm;
        rd += d * d;
        f32x4 s = sqrt4(rd * inv);
        f32x4 ov;
        #pragma unroll
        for (int j = 0; j < 4; ++j) {
            float invs = (s[j] > STD_MIN) ? __builtin_amdgcn_rcpf(s[j]) : 1.0f;
            float v = (xr[r][j] - mean[j]) * invs;
            ov[j] = fminf(fmaxf(v, -MAX_VAL), MAX_VAL);
        }
        __builtin_nontemporal_store(ov, &out[gbase + (size_t)row * CG]);
    }
}

// ======================= fallback: R6 5-kernel path ========================
constexpr int TB = 32;
constexpr int NC = T / TB;     // 256 chunks
constexpr int LSUB = TB;

__device__ inline void decomp(int gtid, int& b, int& k, int& cg) {
    cg = gtid & (CG - 1);
    k  = (gtid / CG) & (NC - 1);
    b  = gtid / (CG * NC);
}

template <bool BYTES>
__global__ __launch_bounds__(256) void k_pass1(
    const f32x4* __restrict__ x, const f32x4* __restrict__ mask,
    f32x4* __restrict__ sumx, f32x4* __restrict__ sumnm,
    unsigned* __restrict__ nmb)
{
    int gtid = blockIdx.x * 256 + threadIdx.x;
    int b, k, cg; decomp(gtid, b, k, cg);
    size_t base = ((size_t)b * T + (size_t)k * LSUB) * CG + cg;
    f32x4 sx = {0,0,0,0}, sn = {0,0,0,0};
    #pragma unroll 8
    for (int t = 0; t < LSUB; ++t) {
        f32x4 xv = x[base + (size_t)t * CG];
        f32x4 mv = mask[base + (size_t)t * CG];
        f32x4 nm = 1.0f - mv;
        if (BYTES) {
            unsigned w = (unsigned)nm[0] | ((unsigned)nm[1] << 8)
                       | ((unsigned)nm[2] << 16) | ((unsigned)nm[3] << 24);
            nmb[base + (size_t)t * CG] = w;
        }
        sx += xv; sn += nm;
    }
    size_t o = ((size_t)b * NC + k) * CG + cg;
    sumx[o] = sx; sumnm[o] = sn;
}

template <int NCOMP>
__device__ inline void block_exscan(float* vals, int lane, int wave)
{
    float inc[NCOMP];
    #pragma unroll
    for (int j = 0; j < NCOMP; ++j) inc[j] = vals[j];
    #pragma unroll
    for (int d = 1; d < 64; d <<= 1) {
        #pragma unroll
        for (int j = 0; j < NCOMP; ++j) {
            float u = __shfl_up(inc[j], d, 64);
            if (lane >= d) inc[j] += u;
        }
    }
    __shared__ float wsum[4][NCOMP];
    if (lane == 63) {
        #pragma unroll
        for (int j = 0; j < NCOMP; ++j) wsum[wave][j] = inc[j];
    }
    __syncthreads();
    float off[NCOMP];
    #pragma unroll
    for (int j = 0; j < NCOMP; ++j) off[j] = 0.0f;
    for (int w = 0; w < wave; ++w) {
        #pragma unroll
        for (int j = 0; j < NCOMP; ++j) off[j] += wsum[w][j];
    }
    #pragma unroll
    for (int j = 0; j < NCOMP; ++j) {
        float e = __shfl_up(inc[j], 1, 64);
        vals[j] = off[j] + ((lane == 0) ? 0.0f : e);
    }
}

__global__ __launch_bounds__(256) void k_scan2(f32x4* __restrict__ a0,
                                               f32x4* __restrict__ a1)
{
    int blk = blockIdx.x, cg = blk & 31, b = blk >> 5;
    int k = threadIdx.x, lane = k & 63, wave = k >> 6;
    size_t o = ((size_t)b * NC + k) * CG + cg;
    f32x4 v0 = a0[o], v1 = a1[o];
    float vals[8] = {v0[0],v0[1],v0[2],v0[3],v1[0],v1[1],v1[2],v1[3]};
    block_exscan<8>(vals, lane, wave);
    a0[o] = (f32x4){vals[0],vals[1],vals[2],vals[3]};
    a1[o] = (f32x4){vals[4],vals[5],vals[6],vals[7]};
}

__global__ __launch_bounds__(256) void k_scan1(f32x4* __restrict__ a0)
{
    int blk = blockIdx.x, cg = blk & 31, b = blk >> 5;
    int k = threadIdx.x, lane = k & 63, wave = k >> 6;
    size_t o = ((size_t)b * NC + k) * CG + cg;
    f32x4 v0 = a0[o];
    float vals[4] = {v0[0],v0[1],v0[2],v0[3]};
    block_exscan<4>(vals, lane, wave);
    a0[o] = (f32x4){vals[0],vals[1],vals[2],vals[3]};
}

__device__ inline f32x4 decode_nm8(unsigned w) {
    f32x4 r;
    #pragma unroll
    for (int j = 0; j < 4; ++j) r[j] = (float)((w >> (8 * j)) & 0xffu);
    return r;
}

template <bool BYTES>
__global__ __launch_bounds__(256) void k_pass3(
    const f32x4* __restrict__ x, const f32x4* __restrict__ mask,
    const unsigned* __restrict__ nmb,
    const f32x4* __restrict__ psumx, const f32x4* __restrict__ psumnm,
    f32x4* __restrict__ sumd2)
{
    int gtid = blockIdx.x * 256 + threadIdx.x;
    int b, k, cg; decomp(gtid, b, k, cg);
    size_t base = ((size_t)b * T + (size_t)k * LSUB) * CG + cg;
    size_t o = ((size_t)b * NC + k) * CG + cg;
    f32x4 rx = psumx[o], rn = psumnm[o];
    f32x4 sd = {0,0,0,0};
    #pragma unroll 8
    for (int t = 0; t < LSUB; ++t) {
        f32x4 xv = x[base + (size_t)t * CG];
        f32x4 nm = BYTES ? decode_nm8(nmb[base + (size_t)t * CG])
                         : (1.0f - mask[base + (size_t)t * CG]);
        rx += xv; rn += nm;
        f32x4 mean = rx * rcp4(sel_neff(rn));
        f32x4 d = (xv - mean) * nm;
        sd += d * d;
    }
    sumd2[o] = sd;
}

template <bool BYTES>
__global__ __launch_bounds__(256) void k_pass5(
    const f32x4* __restrict__ x, const f32x4* __restrict__ mask,
    const unsigned* __restrict__ nmb,
    const f32x4* __restrict__ psumx, const f32x4* __restrict__ psumnm,
    const f32x4* __restrict__ psumd2, f32x4* __restrict__ out)
{
    int gtid = blockIdx.x * 256 + threadIdx.x;
    int b, k, cg; decomp(gtid, b, k, cg);
    size_t base = ((size_t)b * T + (size_t)k * LSUB) * CG + cg;
    size_t o = ((size_t)b * NC + k) * CG + cg;
    f32x4 rx = psumx[o], rn = psumnm[o], rd = psumd2[o];
    #pragma unroll 8
    for (int t = 0; t < LSUB; ++t) {
        f32x4 xv = x[base + (size_t)t * CG];
        f32x4 nm = BYTES ? decode_nm8(nmb[base + (size_t)t * CG])
                         : (1.0f - mask[base + (size_t)t * CG]);
        rx += xv; rn += nm;
        f32x4 inv = rcp4(sel_neff(rn));
        f32x4 mean = rx * inv;
        f32x4 d = (xv - mean) * nm;
        rd += d * d;
        f32x4 s = sqrt4(rd * inv);
        f32x4 ov;
        #pragma unroll
        for (int j = 0; j < 4; ++j) {
            float invs = (s[j] > STD_MIN) ? __builtin_amdgcn_rcpf(s[j]) : 1.0f;
            float v = (xv[j] - mean[j]) * invs;
            ov[j] = fminf(fmaxf(v, -MAX_VAL), MAX_VAL);
        }
        __builtin_nontemporal_store(ov, &out[base + (size_t)t * CG]);
    }
}

template <bool BYTES>
static void run_fallback(const f32x4* x, const f32x4* mask, f32x4* out,
                         void* d_ws, hipStream_t stream)
{
    size_t arr_elems = (size_t)B * NC * C;
    f32x4* sumx  = (f32x4*)d_ws;
    f32x4* sumnm = (f32x4*)((float*)d_ws + arr_elems);
    f32x4* sumd2 = (f32x4*)((float*)d_ws + 2 * arr_elems);
    unsigned* nmb = (unsigned*)((float*)d_ws + 3 * arr_elems);

    int main_blocks = B * NC * CG / 256;
    int scan_blocks = B * CG;

    k_pass1<BYTES><<<main_blocks, 256, 0, stream>>>(x, mask, sumx, sumnm, nmb);
    k_scan2<<<scan_blocks, 256, 0, stream>>>(sumx, sumnm);
    k_pass3<BYTES><<<main_blocks, 256, 0, stream>>>(x, mask, nmb, sumx, sumnm, sumd2);
    k_scan1<<<scan_blocks, 256, 0, stream>>>(sumd2);
    k_pass5<BYTES><<<main_blocks, 256, 0, stream>>>(x, mask, nmb, sumx, sumnm, sumd2, out);
}

// ===========================================================================
extern "C" void kernel_launch(void* const* d_in, const int* in_sizes, int n_in,
                              void* d_out, int out_size, void* d_ws, size_t ws_size,
                              hipStream_t stream) {
    const f32x4* x    = (const f32x4*)d_in[0];
    const f32x4* mask = (const f32x4*)d_in[1];
    f32x4* out = (f32x4*)d_out;

    size_t agg_elems = (size_t)B * NCH * CG;      // 32768 f32x4 per array
    f32x4* aggx = (f32x4*)d_ws;
    f32x4* aggn = aggx + agg_elems;
    f32x4* aggd = aggn + agg_elems;

    bool coop_ok = ws_size >= 3 * agg_elems * sizeof(f32x4);
    if (coop_ok) {
        void* args[] = { (void*)&x, (void*)&mask, (void*)&out,
                         (void*)&aggx, (void*)&aggn, (void*)&aggd };
        hipError_t err = hipLaunchCooperativeKernel(
            reinterpret_cast<const void*>(&k_fused),
            dim3(B * NCH), dim3(256), args, 0, stream);
        if (err == hipSuccess) return;
    }

    size_t need = 3ull * B * NC * C * sizeof(float)
                + (size_t)B * T * CG * sizeof(unsigned);
    if (ws_size >= need) run_fallback<true >(x, mask, out, d_ws, stream);
    else                 run_fallback<false>(x, mask, out, d_ws, stream);
}

// Round 9
// 72.936 us; speedup vs baseline: 7.2656x; 7.2656x over previous
//
#include <hip/hip_runtime.h>
#include <math.h>
#include <stdint.h>

// CausalRevIN: B=16, T=8192, C=128, fp32.
// R9: 3-dispatch structure, 128-row chunks (NCH=64 per batch, grid 1024).
//  k1: cold read x+mask -> per-chunk sums (aggx/aggn) + nm nibbles packed as
//      one uint64 per thread (2 MB total).
//  k2: prologue = parallel predecessor-aggregate prefix (<=63 x 512B, L2);
//      x in regs (single dispatch, no sync-crossing -> no spill); dev2 sums
//      -> aggd.
//  k3: same prologue over 3 arrays; 3 register sweeps; NT output stores.
// Scan dispatches eliminated; nmb shrunk 16MB -> 2MB.
constexpr int B = 16;
constexpr int T = 8192;
constexpr int C = 128;
constexpr int CG = C / 4;        // 32 f32x4 channel-groups
constexpr int TBK = 128;         // rows per chunk/block
constexpr int NCH = T / TBK;     // 64 chunks per batch
constexpr int SUBS = 8;          // 256 threads = SUBS * CG
constexpr int RPT = TBK / SUBS;  // 16 rows per thread
constexpr float STD_MIN = 1e-5f;
constexpr float MAX_VAL = 100.0f;

using f32x4 = __attribute__((ext_vector_type(4))) float;

__device__ inline f32x4 sel_neff(f32x4 n) {
    f32x4 r;
    #pragma unroll
    for (int j = 0; j < 4; ++j) r[j] = (n[j] == 0.0f) ? 1.0f : n[j];
    return r;
}
__device__ inline f32x4 rcp4(f32x4 a) {
    f32x4 r;
    #pragma unroll
    for (int j = 0; j < 4; ++j) r[j] = __builtin_amdgcn_rcpf(a[j]);
    return r;
}
__device__ inline f32x4 sqrt4(f32x4 a) {
    f32x4 r;
    #pragma unroll
    for (int j = 0; j < 4; ++j) r[j] = __builtin_amdgcn_sqrtf(a[j]);
    return r;
}
__device__ inline f32x4 decode_nib(unsigned nib) {
    f32x4 r;
    r[0] = (float)(nib & 1u);
    r[1] = (float)((nib >> 1) & 1u);
    r[2] = (float)((nib >> 2) & 1u);
    r[3] = (float)((nib >> 3) & 1u);
    return r;
}

// ---------------- k1: cold sums + nm nibble pack ---------------------------
__global__ __launch_bounds__(256) void k1_sums(
    const f32x4* __restrict__ x, const f32x4* __restrict__ mask,
    f32x4* __restrict__ aggx, f32x4* __restrict__ aggn,
    uint64_t* __restrict__ nmw)
{
    __shared__ f32x4 p0[SUBS][CG], p1[SUBS][CG];
    int tid = threadIdx.x, cg = tid & 31, sub = tid >> 5;
    int blk = blockIdx.x, b = blk >> 6, k = blk & (NCH - 1);
    size_t base = ((size_t)b * T + (size_t)k * TBK + (size_t)sub * RPT) * CG + cg;

    f32x4 sx = {0,0,0,0}, sn = {0,0,0,0};
    uint64_t w = 0;
    #pragma unroll
    for (int r = 0; r < RPT; ++r) {
        f32x4 xv = x[base + (size_t)r * CG];
        f32x4 mv = mask[base + (size_t)r * CG];
        f32x4 nm = 1.0f - mv;
        sx += xv; sn += nm;
        unsigned nib = (unsigned)nm[0] | ((unsigned)nm[1] << 1)
                     | ((unsigned)nm[2] << 2) | ((unsigned)nm[3] << 3);
        w |= (uint64_t)nib << (4 * r);
    }
    nmw[(size_t)blk * 256 + tid] = w;
    p0[sub][cg] = sx; p1[sub][cg] = sn;
    __syncthreads();
    if (sub == 0) {
        f32x4 tx = p0[0][cg], tn = p1[0][cg];
        #pragma unroll
        for (int s = 1; s < SUBS; ++s) { tx += p0[s][cg]; tn += p1[s][cg]; }
        aggx[(size_t)blk * CG + cg] = tx;
        aggn[(size_t)blk * CG + cg] = tn;
    }
}

// ---------------- k2: dev^2 sums (fused predecessor prefix) ----------------
__global__ __launch_bounds__(256) void k2_dev2(
    const f32x4* __restrict__ x,
    const f32x4* __restrict__ aggx, const f32x4* __restrict__ aggn,
    const uint64_t* __restrict__ nmw, f32x4* __restrict__ aggd)
{
    __shared__ f32x4 p0[SUBS][CG], p1[SUBS][CG];
    int tid = threadIdx.x, cg = tid & 31, sub = tid >> 5;
    int blk = blockIdx.x, b = blk >> 6, k = blk & (NCH - 1);
    size_t base = ((size_t)b * T + (size_t)k * TBK + (size_t)sub * RPT) * CG + cg;

    // predecessor-aggregate prefix (parallel over subs)
    f32x4 pxp = {0,0,0,0}, pnp = {0,0,0,0};
    for (int j = sub; j < k; j += SUBS) {
        size_t o = ((size_t)(b * NCH + j)) * CG + cg;
        pxp += aggx[o]; pnp += aggn[o];
    }
    p0[sub][cg] = pxp; p1[sub][cg] = pnp;
    __syncthreads();
    f32x4 px = p0[0][cg], pn = p1[0][cg];
    #pragma unroll
    for (int s = 1; s < SUBS; ++s) { px += p0[s][cg]; pn += p1[s][cg]; }

    // intra-chunk: load x into regs + nm word
    f32x4 xr[RPT];
    #pragma unroll
    for (int r = 0; r < RPT; ++r) xr[r] = x[base + (size_t)r * CG];
    uint64_t w = nmw[(size_t)blk * 256 + tid];

    // sweep1: per-thread sums -> intra-chunk exclusive offsets
    f32x4 sx = {0,0,0,0}, sn = {0,0,0,0};
    #pragma unroll
    for (int r = 0; r < RPT; ++r) {
        sx += xr[r];
        sn += decode_nib((unsigned)(w >> (4 * r)) & 0xFu);
    }
    __syncthreads();
    p0[sub][cg] = sx; p1[sub][cg] = sn;
    __syncthreads();
    f32x4 offx = {0,0,0,0}, offn = {0,0,0,0};
    for (int s = 0; s < sub; ++s) { offx += p0[s][cg]; offn += p1[s][cg]; }

    // sweep2: running mean -> dev^2 sums
    f32x4 rx = px + offx, rn = pn + offn, sd = {0,0,0,0};
    #pragma unroll
    for (int r = 0; r < RPT; ++r) {
        f32x4 nm = decode_nib((unsigned)(w >> (4 * r)) & 0xFu);
        rx += xr[r]; rn += nm;
        f32x4 mean = rx * rcp4(sel_neff(rn));
        f32x4 d = (xr[r] - mean) * nm;
        sd += d * d;
    }
    __syncthreads();
    p0[sub][cg] = sd;
    __syncthreads();
    if (sub == 0) {
        f32x4 td = p0[0][cg];
        #pragma unroll
        for (int s = 1; s < SUBS; ++s) td += p0[s][cg];
        aggd[(size_t)blk * CG + cg] = td;
    }
}

// ---------------- k3: finalize + clip, NT stores ---------------------------
__global__ __launch_bounds__(256) void k3_final(
    const f32x4* __restrict__ x,
    const f32x4* __restrict__ aggx, const f32x4* __restrict__ aggn,
    const f32x4* __restrict__ aggd, const uint64_t* __restrict__ nmw,
    f32x4* __restrict__ out)
{
    __shared__ f32x4 p0[SUBS][CG], p1[SUBS][CG], p2[SUBS][CG];
    int tid = threadIdx.x, cg = tid & 31, sub = tid >> 5;
    int blk = blockIdx.x, b = blk >> 6, k = blk & (NCH - 1);
    size_t base = ((size_t)b * T + (size_t)k * TBK + (size_t)sub * RPT) * CG + cg;

    // predecessor prefixes for x, nm, d2
    f32x4 pxp = {0,0,0,0}, pnp = {0,0,0,0}, pdp = {0,0,0,0};
    for (int j = sub; j < k; j += SUBS) {
        size_t o = ((size_t)(b * NCH + j)) * CG + cg;
        pxp += aggx[o]; pnp += aggn[o]; pdp += aggd[o];
    }
    p0[sub][cg] = pxp; p1[sub][cg] = pnp; p2[sub][cg] = pdp;
    __syncthreads();
    f32x4 px = p0[0][cg], pn = p1[0][cg], pd = p2[0][cg];
    #pragma unroll
    for (int s = 1; s < SUBS; ++s) {
        px += p0[s][cg]; pn += p1[s][cg]; pd += p2[s][cg];
    }

    f32x4 xr[RPT];
    #pragma unroll
    for (int r = 0; r < RPT; ++r) xr[r] = x[base + (size_t)r * CG];
    uint64_t w = nmw[(size_t)blk * 256 + tid];

    // sweep1: sums -> intra offsets for x, nm
    f32x4 sx = {0,0,0,0}, sn = {0,0,0,0};
    #pragma unroll
    for (int r = 0; r < RPT; ++r) {
        sx += xr[r];
        sn += decode_nib((unsigned)(w >> (4 * r)) & 0xFu);
    }
    __syncthreads();
    p0[sub][cg] = sx; p1[sub][cg] = sn;
    __syncthreads();
    f32x4 offx = {0,0,0,0}, offn = {0,0,0,0};
    for (int s = 0; s < sub; ++s) { offx += p0[s][cg]; offn += p1[s][cg]; }
    f32x4 rx0 = px + offx, rn0 = pn + offn;

    // sweep2: per-thread dev^2 total -> intra offset for d2
    f32x4 rx = rx0, rn = rn0, sd = {0,0,0,0};
    #pragma unroll
    for (int r = 0; r < RPT; ++r) {
        f32x4 nm = decode_nib((unsigned)(w >> (4 * r)) & 0xFu);
        rx += xr[r]; rn += nm;
        f32x4 mean = rx * rcp4(sel_neff(rn));
        f32x4 d = (xr[r] - mean) * nm;
        sd += d * d;
    }
    __syncthreads();
    p0[sub][cg] = sd;
    __syncthreads();
    f32x4 offd = {0,0,0,0};
    for (int s = 0; s < sub; ++s) offd += p0[s][cg];
    f32x4 rd = pd + offd;

    // sweep3: recompute running stats, finalize, NT store
    rx = rx0; rn = rn0;
    #pragma unroll
    for (int r = 0; r < RPT; ++r) {
        f32x4 nm = decode_nib((unsigned)(w >> (4 * r)) & 0xFu);
        rx += xr[r]; rn += nm;
        f32x4 inv = rcp4(sel_neff(rn));
        f32x4 mean = rx * inv;
        f32x4 d = (xr[r] - mean) * nm;
        rd += d * d;
        f32x4 s = sqrt4(rd * inv);
        f32x4 ov;
        #pragma unroll
        for (int j = 0; j < 4; ++j) {
            float invs = (s[j] > STD_MIN) ? __builtin_amdgcn_rcpf(s[j]) : 1.0f;
            float v = (xr[r][j] - mean[j]) * invs;
            ov[j] = fminf(fmaxf(v, -MAX_VAL), MAX_VAL);
        }
        __builtin_nontemporal_store(ov, &out[base + (size_t)r * CG]);
    }
}

// ===========================================================================
extern "C" void kernel_launch(void* const* d_in, const int* in_sizes, int n_in,
                              void* d_out, int out_size, void* d_ws, size_t ws_size,
                              hipStream_t stream) {
    const f32x4* x    = (const f32x4*)d_in[0];
    const f32x4* mask = (const f32x4*)d_in[1];
    f32x4* out = (f32x4*)d_out;

    // ws layout: aggx/aggn/aggd (1024*CG f32x4 = 512 KB each), nmw (2 MB)
    size_t agg_elems = (size_t)B * NCH * CG;
    f32x4* aggx = (f32x4*)d_ws;
    f32x4* aggn = aggx + agg_elems;
    f32x4* aggd = aggn + agg_elems;
    uint64_t* nmw = (uint64_t*)(aggd + agg_elems);

    int grid = B * NCH;   // 1024

    k1_sums<<<grid, 256, 0, stream>>>(x, mask, aggx, aggn, nmw);
    k2_dev2<<<grid, 256, 0, stream>>>(x, aggx, aggn, nmw, aggd);
    k3_final<<<grid, 256, 0, stream>>>(x, aggx, aggn, aggd, nmw, out);
}

// Round 10
// 71.530 us; speedup vs baseline: 7.4084x; 1.0197x over previous
//
#include <hip/hip_runtime.h>
#include <math.h>
#include <stdint.h>

// CausalRevIN: B=16, T=8192, C=128, fp32.
// R10: 3 dispatches, each single-sweep over x.
//  k1 (cold window, rate-capped by harness fill): x+mask -> chunk aggregates
//     aggx/aggn + PER-SUB partials subx/subn + nm nibbles (uint64/thread).
//  k2: chunk-prefix prologue + own-sub offsets (from subx/subn) + one dev^2
//     sweep -> aggd + subd.  (no intra sweep1)
//  k3: 3-array prologue + offsets (subx/subn/subd) + one finalize sweep with
//     NT stores.  (no sweep1, no sweep2 -> 16 fewer rcps, no LDS offsets)
// neff = fmaxf(n,1) (bit-identical to n==0?1:n for counts).
constexpr int B = 16;
constexpr int T = 8192;
constexpr int C = 128;
constexpr int CG = C / 4;        // 32 f32x4 channel-groups
constexpr int TBK = 128;         // rows per chunk/block
constexpr int NCH = T / TBK;     // 64 chunks per batch
constexpr int SUBS = 8;          // 256 threads = SUBS * CG
constexpr int RPT = TBK / SUBS;  // 16 rows per thread
constexpr float STD_MIN = 1e-5f;
constexpr float MAX_VAL = 100.0f;

using f32x4 = __attribute__((ext_vector_type(4))) float;

__device__ inline f32x4 max1(f32x4 n) {
    f32x4 r;
    #pragma unroll
    for (int j = 0; j < 4; ++j) r[j] = fmaxf(n[j], 1.0f);
    return r;
}
__device__ inline f32x4 rcp4(f32x4 a) {
    f32x4 r;
    #pragma unroll
    for (int j = 0; j < 4; ++j) r[j] = __builtin_amdgcn_rcpf(a[j]);
    return r;
}
__device__ inline f32x4 sqrt4(f32x4 a) {
    f32x4 r;
    #pragma unroll
    for (int j = 0; j < 4; ++j) r[j] = __builtin_amdgcn_sqrtf(a[j]);
    return r;
}
__device__ inline f32x4 decode_nib(unsigned nib) {
    f32x4 r;
    r[0] = (float)(nib & 1u);
    r[1] = (float)((nib >> 1) & 1u);
    r[2] = (float)((nib >> 2) & 1u);
    r[3] = (float)((nib >> 3) & 1u);
    return r;
}

// ---------------- k1: cold sums + sub partials + nm nibbles ----------------
__global__ __launch_bounds__(256) void k1_sums(
    const f32x4* __restrict__ x, const f32x4* __restrict__ mask,
    f32x4* __restrict__ aggx, f32x4* __restrict__ aggn,
    f32x4* __restrict__ subx, f32x4* __restrict__ subn,
    uint64_t* __restrict__ nmw)
{
    __shared__ f32x4 p0[SUBS][CG], p1[SUBS][CG];
    int tid = threadIdx.x, cg = tid & 31, sub = tid >> 5;
    int blk = blockIdx.x, b = blk >> 6, k = blk & (NCH - 1);
    size_t base = ((size_t)b * T + (size_t)k * TBK + (size_t)sub * RPT) * CG + cg;

    f32x4 sx = {0,0,0,0}, sn = {0,0,0,0};
    uint64_t w = 0;
    #pragma unroll
    for (int r = 0; r < RPT; ++r) {
        f32x4 xv = x[base + (size_t)r * CG];
        f32x4 mv = mask[base + (size_t)r * CG];
        f32x4 nm = 1.0f - mv;
        sx += xv; sn += nm;
        unsigned nib = (unsigned)nm[0] | ((unsigned)nm[1] << 1)
                     | ((unsigned)nm[2] << 2) | ((unsigned)nm[3] << 3);
        w |= (uint64_t)nib << (4 * r);
    }
    nmw[(size_t)blk * 256 + tid] = w;
    size_t so = ((size_t)blk * SUBS + sub) * CG + cg;
    subx[so] = sx;
    subn[so] = sn;
    p0[sub][cg] = sx; p1[sub][cg] = sn;
    __syncthreads();
    if (sub == 0) {
        f32x4 tx = p0[0][cg], tn = p1[0][cg];
        #pragma unroll
        for (int s = 1; s < SUBS; ++s) { tx += p0[s][cg]; tn += p1[s][cg]; }
        aggx[(size_t)blk * CG + cg] = tx;
        aggn[(size_t)blk * CG + cg] = tn;
    }
}

// ---------------- k2: single dev^2 sweep -----------------------------------
__global__ __launch_bounds__(256) void k2_dev2(
    const f32x4* __restrict__ x,
    const f32x4* __restrict__ aggx, const f32x4* __restrict__ aggn,
    const f32x4* __restrict__ subx, const f32x4* __restrict__ subn,
    const uint64_t* __restrict__ nmw,
    f32x4* __restrict__ aggd, f32x4* __restrict__ subd)
{
    __shared__ f32x4 p0[SUBS][CG], p1[SUBS][CG];
    int tid = threadIdx.x, cg = tid & 31, sub = tid >> 5;
    int blk = blockIdx.x, b = blk >> 6, k = blk & (NCH - 1);
    size_t base = ((size_t)b * T + (size_t)k * TBK + (size_t)sub * RPT) * CG + cg;

    // chunk-level predecessor prefix (parallel over subs)
    f32x4 pxp = {0,0,0,0}, pnp = {0,0,0,0};
    for (int j = sub; j < k; j += SUBS) {
        size_t o = ((size_t)(b * NCH + j)) * CG + cg;
        pxp += aggx[o]; pnp += aggn[o];
    }
    p0[sub][cg] = pxp; p1[sub][cg] = pnp;
    __syncthreads();
    f32x4 px = p0[0][cg], pn = p1[0][cg];
    #pragma unroll
    for (int s = 1; s < SUBS; ++s) { px += p0[s][cg]; pn += p1[s][cg]; }

    // own-chunk exclusive sub offsets (from k1's partials)
    f32x4 offx = {0,0,0,0}, offn = {0,0,0,0};
    for (int s = 0; s < sub; ++s) {
        size_t so = ((size_t)blk * SUBS + s) * CG + cg;
        offx += subx[so]; offn += subn[so];
    }
    f32x4 rx = px + offx, rn = pn + offn;
    uint64_t w = nmw[(size_t)blk * 256 + tid];

    // single sweep: running mean -> dev^2 sums
    f32x4 sd = {0,0,0,0};
    #pragma unroll
    for (int r = 0; r < RPT; ++r) {
        f32x4 xv = x[base + (size_t)r * CG];
        f32x4 nm = decode_nib((unsigned)(w >> (4 * r)) & 0xFu);
        rx += xv; rn += nm;
        f32x4 mean = rx * rcp4(max1(rn));
        f32x4 d = (xv - mean) * nm;
        sd += d * d;
    }
    subd[((size_t)blk * SUBS + sub) * CG + cg] = sd;
    __syncthreads();            // before p0 reuse
    p0[sub][cg] = sd;
    __syncthreads();
    if (sub == 0) {
        f32x4 td = p0[0][cg];
        #pragma unroll
        for (int s = 1; s < SUBS; ++s) td += p0[s][cg];
        aggd[(size_t)blk * CG + cg] = td;
    }
}

// ---------------- k3: single finalize sweep, NT stores ---------------------
__global__ __launch_bounds__(256) void k3_final(
    const f32x4* __restrict__ x,
    const f32x4* __restrict__ aggx, const f32x4* __restrict__ aggn,
    const f32x4* __restrict__ aggd,
    const f32x4* __restrict__ subx, const f32x4* __restrict__ subn,
    const f32x4* __restrict__ subd,
    const uint64_t* __restrict__ nmw, f32x4* __restrict__ out)
{
    __shared__ f32x4 p0[SUBS][CG], p1[SUBS][CG], p2[SUBS][CG];
    int tid = threadIdx.x, cg = tid & 31, sub = tid >> 5;
    int blk = blockIdx.x, b = blk >> 6, k = blk & (NCH - 1);
    size_t base = ((size_t)b * T + (size_t)k * TBK + (size_t)sub * RPT) * CG + cg;

    // chunk-level predecessor prefixes (x, nm, d2)
    f32x4 pxp = {0,0,0,0}, pnp = {0,0,0,0}, pdp = {0,0,0,0};
    for (int j = sub; j < k; j += SUBS) {
        size_t o = ((size_t)(b * NCH + j)) * CG + cg;
        pxp += aggx[o]; pnp += aggn[o]; pdp += aggd[o];
    }
    p0[sub][cg] = pxp; p1[sub][cg] = pnp; p2[sub][cg] = pdp;
    __syncthreads();
    f32x4 px = p0[0][cg], pn = p1[0][cg], pd = p2[0][cg];
    #pragma unroll
    for (int s = 1; s < SUBS; ++s) {
        px += p0[s][cg]; pn += p1[s][cg]; pd += p2[s][cg];
    }

    // own-chunk exclusive sub offsets
    f32x4 offx = {0,0,0,0}, offn = {0,0,0,0}, offd = {0,0,0,0};
    for (int s = 0; s < sub; ++s) {
        size_t so = ((size_t)blk * SUBS + s) * CG + cg;
        offx += subx[so]; offn += subn[so]; offd += subd[so];
    }
    f32x4 rx = px + offx, rn = pn + offn, rd = pd + offd;
    uint64_t w = nmw[(size_t)blk * 256 + tid];

    // single sweep: finalize + clip + NT store
    #pragma unroll
    for (int r = 0; r < RPT; ++r) {
        f32x4 xv = x[base + (size_t)r * CG];
        f32x4 nm = decode_nib((unsigned)(w >> (4 * r)) & 0xFu);
        rx += xv; rn += nm;
        f32x4 inv = rcp4(max1(rn));
        f32x4 mean = rx * inv;
        f32x4 d = (xv - mean) * nm;
        rd += d * d;
        f32x4 s = sqrt4(rd * inv);
        f32x4 ov;
        #pragma unroll
        for (int j = 0; j < 4; ++j) {
            float invs = (s[j] > STD_MIN) ? __builtin_amdgcn_rcpf(s[j]) : 1.0f;
            float v = (xv[j] - mean[j]) * invs;
            ov[j] = fminf(fmaxf(v, -MAX_VAL), MAX_VAL);
        }
        __builtin_nontemporal_store(ov, &out[base + (size_t)r * CG]);
    }
}

// ===========================================================================
extern "C" void kernel_launch(void* const* d_in, const int* in_sizes, int n_in,
                              void* d_out, int out_size, void* d_ws, size_t ws_size,
                              hipStream_t stream) {
    const f32x4* x    = (const f32x4*)d_in[0];
    const f32x4* mask = (const f32x4*)d_in[1];
    f32x4* out = (f32x4*)d_out;

    // ws: aggx/aggn/aggd (512 KB each) + subx/subn/subd (4 MB each) + nmw (2 MB)
    size_t agg_elems = (size_t)B * NCH * CG;          // 32768 f32x4
    size_t sub_elems = (size_t)B * NCH * SUBS * CG;   // 262144 f32x4
    f32x4* aggx = (f32x4*)d_ws;
    f32x4* aggn = aggx + agg_elems;
    f32x4* aggd = aggn + agg_elems;
    f32x4* subx = aggd + agg_elems;
    f32x4* subn = subx + sub_elems;
    f32x4* subd = subn + sub_elems;
    uint64_t* nmw = (uint64_t*)(subd + sub_elems);

    int grid = B * NCH;   // 1024

    k1_sums<<<grid, 256, 0, stream>>>(x, mask, aggx, aggn, subx, subn, nmw);
    k2_dev2<<<grid, 256, 0, stream>>>(x, aggx, aggn, subx, subn, nmw, aggd, subd);
    k3_final<<<grid, 256, 0, stream>>>(x, aggx, aggn, aggd, subx, subn, subd, nmw, out);
}